// Round 2
// baseline (1710.707 us; speedup 1.0000x reference)
//
#include <hip/hip_runtime.h>
#include <math.h>

// Problem constants (fixed by setup_inputs)
#define BB 128
#define LFULL 257
#define LW 256     // L-1 words
#define TT 1024    // video frames
#define CC 256     // hidden
#define NH 8
#define DHD 32
#define PP 8       // NUM_PHRASE
#define NLAY 3

// ---------------- block reduce helpers (blockDim == 256 -> 4 waves) -------------
__device__ __forceinline__ float blockReduceSum(float v, volatile float* lds) {
#pragma unroll
    for (int m = 32; m >= 1; m >>= 1) v += __shfl_xor(v, m);
    __syncthreads();
    if ((threadIdx.x & 63) == 0) lds[threadIdx.x >> 6] = v;
    __syncthreads();
    return lds[0] + lds[1] + lds[2] + lds[3];
}
__device__ __forceinline__ float blockReduceMax(float v, volatile float* lds) {
#pragma unroll
    for (int m = 32; m >= 1; m >>= 1) v = fmaxf(v, __shfl_xor(v, m));
    __syncthreads();
    if ((threadIdx.x & 63) == 0) lds[threadIdx.x >> 6] = v;
    __syncthreads();
    return fmaxf(fmaxf(lds[0], lds[1]), fmaxf(lds[2], lds[3]));
}

// ---------------- fp32 tiled GEMM: C = A @ B (+bias) (+relu) -------------------
// 64x64 tile, BK=16, 256 threads, 4x4 micro-tile per thread.
// TRANSB=0: B is (K,N) row-major. TRANSB=1: B is (N,K) row-major (C = A @ B^T).
// batch via blockIdx.z with element strides sA/sB/sC.
#define GTS 64
#define GKT 16
#define GPAD 68

template<int TRANSB, int RELU>
__global__ __launch_bounds__(256) void gemm_f32(
    const float* __restrict__ A, int lda, long long sA,
    const float* __restrict__ Bm, int ldb, long long sB,
    const float* __restrict__ bias,
    float* __restrict__ C, int ldc, long long sC,
    int M, int N, int K)
{
    __shared__ float As[GKT][GPAD];
    __shared__ float Bs[GKT][GPAD];
    const int tid = threadIdx.x;
    const int tx = tid & 15, ty = tid >> 4;
    const int n0 = blockIdx.x * GTS;
    const int m0 = blockIdx.y * GTS;
    const long long bz = blockIdx.z;
    const float* Ab = A + bz * sA;
    const float* Bb = Bm + bz * sB;
    float* Cb = C + bz * sC;

    const int lr = tid >> 2;           // 0..63
    const int lc = (tid & 3) << 2;     // 0,4,8,12
    const int br = tid >> 4;           // 0..15
    const int bc = (tid & 15) << 2;    // 0..60

    float acc[4][4] = {};

    for (int k0 = 0; k0 < K; k0 += GKT) {
        float4 a = *(const float4*)&Ab[(long long)(m0 + lr) * lda + k0 + lc];
        As[lc + 0][lr] = a.x; As[lc + 1][lr] = a.y;
        As[lc + 2][lr] = a.z; As[lc + 3][lr] = a.w;
        if (TRANSB) {
            float4 b = *(const float4*)&Bb[(long long)(n0 + lr) * ldb + k0 + lc];
            Bs[lc + 0][lr] = b.x; Bs[lc + 1][lr] = b.y;
            Bs[lc + 2][lr] = b.z; Bs[lc + 3][lr] = b.w;
        } else {
            float4 b = *(const float4*)&Bb[(long long)(k0 + br) * ldb + n0 + bc];
            *(float4*)&Bs[br][bc] = b;
        }
        __syncthreads();
#pragma unroll
        for (int k = 0; k < GKT; ++k) {
            float4 av = *(const float4*)&As[k][ty << 2];
            float4 bv = *(const float4*)&Bs[k][tx << 2];
            float ar[4] = {av.x, av.y, av.z, av.w};
            float brr[4] = {bv.x, bv.y, bv.z, bv.w};
#pragma unroll
            for (int i = 0; i < 4; ++i)
#pragma unroll
                for (int j = 0; j < 4; ++j)
                    acc[i][j] = fmaf(ar[i], brr[j], acc[i][j]);
        }
        __syncthreads();
    }

    float bbr[4] = {0.f, 0.f, 0.f, 0.f};
    if (bias) {
        float4 bb = *(const float4*)&bias[n0 + (tx << 2)];
        bbr[0] = bb.x; bbr[1] = bb.y; bbr[2] = bb.z; bbr[3] = bb.w;
    }
#pragma unroll
    for (int i = 0; i < 4; ++i) {
        float o[4];
#pragma unroll
        for (int j = 0; j < 4; ++j) {
            o[j] = acc[i][j] + bbr[j];
            if (RELU) o[j] = fmaxf(o[j], 0.f);
        }
        float4 ov = make_float4(o[0], o[1], o[2], o[3]);
        *(float4*)&Cb[(long long)(m0 + (ty << 2) + i) * ldc + n0 + (tx << 2)] = ov;
    }
}

// ---------------- word_pe = txt_emb[:,1:] + sine_pos(word_mask) ----------------
// masks are int32 (harness: integer inputs -> const int*)
__global__ __launch_bounds__(256) void word_pe_kernel(
    const float* __restrict__ te, const int* __restrict__ tm,
    float* __restrict__ wpe)
{
    int b = blockIdx.x;
    int c = threadIdx.x;
    __shared__ float cums[LW];
    const int* m = tm + (long long)b * LFULL + 1;
    int s = 0;
    for (int i = 0; i <= c; ++i) s += (m[i] != 0);
    cums[c] = (float)s;
    __syncthreads();
    int i2 = c & ~1;
    float freq = powf(10000.0f, (float)i2 / (float)CC);
    const float* src = te + ((long long)b * LFULL + 1) * CC + c;
    float* dst = wpe + (long long)b * LW * CC + c;
    for (int l = 0; l < LW; ++l) {
        float arg = cums[l] / freq;
        float pe = (c & 1) ? cosf(arg) : sinf(arg);
        dst[(long long)l * CC] = src[(long long)l * CC] + pe;
    }
}

// ---------------- in-place softmax over T + entropy (one block per (b,l)) ------
__global__ __launch_bounds__(256) void softmax_entropy_kernel(
    float* __restrict__ attn, const int* __restrict__ vmask,
    float* __restrict__ ent)
{
    __shared__ float lds[4];
    long long row = blockIdx.x;             // b*256 + l
    int b = blockIdx.x >> 8;
    float* p = attn + row * TT;
    const int* m = vmask + (long long)b * TT;
    int t4 = threadIdx.x * 4;
    float4 v = *(const float4*)&p[t4];
    int4 mm4 = *(const int4*)&m[t4];
    float x[4];
    x[0] = mm4.x ? v.x : -INFINITY;
    x[1] = mm4.y ? v.y : -INFINITY;
    x[2] = mm4.z ? v.z : -INFINITY;
    x[3] = mm4.w ? v.w : -INFINITY;
    float mx = fmaxf(fmaxf(x[0], x[1]), fmaxf(x[2], x[3]));
    mx = blockReduceMax(mx, lds);
    float e[4];
    float ps = 0.f;
#pragma unroll
    for (int j = 0; j < 4; ++j) { e[j] = expf(x[j] - mx); ps += e[j]; }
    float sum = blockReduceSum(ps, lds);
    float q[4];
    float ce = 0.f;
#pragma unroll
    for (int j = 0; j < 4; ++j) {
        q[j] = e[j] / sum;
        ce += q[j] * logf(q[j] + 1e-6f);
    }
    ce = blockReduceSum(ce, lds);
    *(float4*)&p[t4] = make_float4(q[0], q[1], q[2], q[3]);
    if (threadIdx.x == 0) ent[row] = -ce;
}

// ---------------- greedy selection (one block per batch) -----------------------
__global__ __launch_bounds__(256) void select_kernel(
    const float* __restrict__ ent, const int* __restrict__ tm,
    int* __restrict__ sel)
{
    int b = blockIdx.x;
    int l = threadIdx.x;
    __shared__ float sc[LW];
    __shared__ int ord[LW];
    __shared__ unsigned char mk[LW];
    mk[l] = (tm[(long long)b * LFULL + 1 + l] != 0);
    sc[l] = mk[l] ? ent[(long long)b * LW + l] : -INFINITY;
    __syncthreads();
    float mys = sc[l];
    int r = 0;
    for (int j = 0; j < LW; ++j) {
        float s = sc[j];
        r += (s > mys) || (s == mys && j < l);   // stable descending (argsort(-score))
    }
    ord[r] = l;
    __syncthreads();
    if (l == 0) {
        int chosen[PP];
        int cnt = 0;
        for (int t = 0; t < LW; ++t) {
            int idx = ord[t];
            if (!mk[idx]) continue;
            if (cnt >= PP) break;
            bool ok = true;
            for (int s2 = 0; s2 < cnt; ++s2) {
                int d = idx - chosen[s2];
                if (d < 0) d = -d;
                if (d < 2) ok = false;           // MIN_DIST
            }
            if (ok) chosen[cnt++] = idx;
        }
        int last = (cnt > 0) ? chosen[cnt - 1] : -1;
        for (int p = 0; p < PP; ++p)
            sel[b * PP + p] = (p < cnt) ? chosen[p] : last;
    }
}

// ---------------- gather selected rows of word_pe ------------------------------
__global__ __launch_bounds__(256) void gather_kernel(
    const float* __restrict__ wpe, const int* __restrict__ sel,
    float* __restrict__ x0)
{
    int g = blockIdx.x * 256 + threadIdx.x;   // B*P*C = 262144
    int b = g >> 11;
    int p = (g >> 8) & 7;
    int c = g & 255;
    int idx = sel[b * PP + p];
    if (idx < 0) idx = 0;
    x0[g] = wpe[((long long)b * LW + idx) * CC + c];
}

// ---------------- effective biases: b_eff = srcb @ in_w_part + in_b_part -------
__global__ __launch_bounds__(256) void eff_bias_kernel(
    const float* __restrict__ qb, const float* __restrict__ kvb,
    const float* __restrict__ inw, const float* __restrict__ inb,
    float* __restrict__ bq, float* __restrict__ bk, float* __restrict__ bv)
{
    int which = blockIdx.x;
    int n = threadIdx.x;
    const float* srcb;
    int co;
    float* dst;
    if (which == 0)      { srcb = qb;        co = 0;   dst = bq; }
    else if (which == 1) { srcb = kvb;       co = 256; dst = bk; }
    else                 { srcb = kvb + 256; co = 512; dst = bv; }
    float s = inb[co + n];
    for (int k = 0; k < CC; ++k)
        s = fmaf(srcb[k], inw[(long long)k * 768 + co + n], s);
    dst[n] = s;
}

// ---------------- attention scores + softmax (block per (b,h)) -----------------
__global__ __launch_bounds__(256) void attn_scores_kernel(
    const float* __restrict__ qp, const float* __restrict__ KP,
    const int* __restrict__ tm, float* __restrict__ attn)
{
    int b = blockIdx.x, h = blockIdx.y;
    int tid = threadIdx.x;
    __shared__ float qs[PP][DHD];
    __shared__ float sc[PP][LW];
    __shared__ float mxs[PP], sms[PP];
    {
        int q = tid >> 5, d = tid & 31;
        qs[q][d] = qp[((long long)(b * PP + q)) * CC + h * DHD + d];
    }
    __syncthreads();
    // scores for key k = tid
    const float* kr = KP + ((long long)(b * LW + tid)) * CC + h * DHD;
    float kreg[DHD];
#pragma unroll
    for (int j = 0; j < 8; ++j) {
        float4 f = *(const float4*)&kr[j * 4];
        kreg[j * 4 + 0] = f.x; kreg[j * 4 + 1] = f.y;
        kreg[j * 4 + 2] = f.z; kreg[j * 4 + 3] = f.w;
    }
    bool mk = tm[(long long)b * LFULL + 1 + tid] != 0;
#pragma unroll
    for (int q = 0; q < PP; ++q) {
        float s = 0.f;
#pragma unroll
        for (int d = 0; d < DHD; ++d) s = fmaf(qs[q][d], kreg[d], s);
        sc[q][tid] = mk ? s * 0.17677669529663687f : -INFINITY;  // 1/sqrt(32)
    }
    __syncthreads();
    {   // softmax stats: 32 lanes per q
        int q = tid >> 5, j = tid & 31;
        float m = -INFINITY;
        for (int kk = j; kk < LW; kk += 32) m = fmaxf(m, sc[q][kk]);
#pragma unroll
        for (int mm = 16; mm >= 1; mm >>= 1) m = fmaxf(m, __shfl_xor(m, mm, 32));
        float s = 0.f;
        for (int kk = j; kk < LW; kk += 32) s += expf(sc[q][kk] - m);
#pragma unroll
        for (int mm = 16; mm >= 1; mm >>= 1) s += __shfl_xor(s, mm, 32);
        if (j == 0) { mxs[q] = m; sms[q] = s; }
    }
    __syncthreads();
#pragma unroll
    for (int q = 0; q < PP; ++q) {
        float pv = expf(sc[q][tid] - mxs[q]) / sms[q];
        attn[(((long long)(b * NH + h)) * PP + q) * LW + tid] = pv;
    }
}

// ---------------- attn @ V (block per (b,q)) -----------------------------------
__global__ __launch_bounds__(256) void attn_out_kernel(
    const float* __restrict__ attn, const float* __restrict__ VP,
    float* __restrict__ aout)
{
    int b = blockIdx.x, q = blockIdx.y;
    int c = threadIdx.x, h = c >> 5;
    __shared__ float att[NH][LW];
#pragma unroll
    for (int hh = 0; hh < NH; ++hh)
        att[hh][c] = attn[(((long long)(b * NH + hh)) * PP + q) * LW + c];
    __syncthreads();
    const float* vpb = VP + (long long)b * LW * CC + c;
    float acc = 0.f;
#pragma unroll 8
    for (int k = 0; k < LW; ++k)
        acc = fmaf(att[h][k], vpb[(long long)k * CC], acc);
    aout[((long long)(b * PP + q)) * CC + c] = acc;
}

// ---------------- slot_sim = mean over heads -----------------------------------
__global__ __launch_bounds__(256) void slot_sim_kernel(
    const float* __restrict__ attn, float* __restrict__ outs)
{
    int b = blockIdx.x, q = blockIdx.y, k = threadIdx.x;
    float s = 0.f;
#pragma unroll
    for (int h = 0; h < NH; ++h)
        s += attn[(((long long)(b * NH + h)) * PP + q) * LW + k];
    outs[((long long)(b * PP + q)) * LW + k] = s * 0.125f;
}

// ---------------- residual + layer norm ----------------------------------------
__global__ __launch_bounds__(256) void ln_residual_kernel(
    const float* __restrict__ xin, const float* __restrict__ add,
    const float* __restrict__ g, const float* __restrict__ bta,
    float* __restrict__ out)
{
    __shared__ float lds[4];
    int r = blockIdx.x, c = threadIdx.x;
    long long idx = (long long)r * CC + c;
    float v = xin[idx] + add[idx];
    float s = blockReduceSum(v, lds);
    float mu = s * (1.0f / (float)CC);
    float d = v - mu;
    float var = blockReduceSum(d * d, lds) * (1.0f / (float)CC);
    out[idx] = d / sqrtf(var + 1e-5f) * g[c] + bta[c];
}

// ---------------- eos broadcast -------------------------------------------------
__global__ __launch_bounds__(256) void eos_kernel(
    const float* __restrict__ eos, float* __restrict__ outp)
{
    outp[(long long)blockIdx.x * CC + threadIdx.x] = eos[threadIdx.x];
}

// =================================================================================
extern "C" void kernel_launch(void* const* d_in, const int* in_sizes, int n_in,
                              void* d_out, int out_size, void* d_ws, size_t ws_size,
                              hipStream_t stream) {
    const float* txt_emb     = (const float*)d_in[0];
    const int*   txt_mask    = (const int*)d_in[1];     // bool -> int32 per harness
    const float* video_feats = (const float*)d_in[2];
    const int*   video_mask  = (const int*)d_in[3];     // bool -> int32 per harness
    const float* word_proj_w = (const float*)d_in[4];
    const float* word_proj_b = (const float*)d_in[5];
    const float* video_proj_w = (const float*)d_in[6];
    // const float* video_proj_b = (const float*)d_in[7]; // drops out: per-row shift, softmax-invariant
    const float* q_w   = (const float*)d_in[8];
    const float* q_b   = (const float*)d_in[9];
    const float* kv_w  = (const float*)d_in[10];
    const float* kv_b  = (const float*)d_in[11];
    const float* in_w  = (const float*)d_in[12];
    const float* in_b  = (const float*)d_in[13];
    const float* out_w = (const float*)d_in[14];
    const float* out_b = (const float*)d_in[15];
    const float* ln0_g = (const float*)d_in[16];
    const float* ln0_b = (const float*)d_in[17];
    const float* lin_w = (const float*)d_in[18];
    const float* lin_b = (const float*)d_in[19];
    const float* ln1_g = (const float*)d_in[20];
    const float* ln1_b = (const float*)d_in[21];
    const float* eos_slot = (const float*)d_in[22];

    // workspace layout (floats); ~117 MiB total
    float* ws = (float*)d_ws;
    float* word_pe = ws + 0LL;             // 8388608
    float* wp      = ws + 8388608LL;       // 8388608 (later: KP)
    float* U       = ws + 16777216LL;      // 8388608 (later: VP)
    float* ent     = ws + 25165824LL;      // 32768
    int*   sel     = (int*)(ws + 25198592LL); // 1024
    float* x0      = ws + 25199616LL;      // 262144
    float* x1      = ws + 25461760LL;      // 262144
    float* xmid    = ws + 25723904LL;      // 262144
    float* qp      = ws + 25986048LL;      // 262144
    float* attnw   = ws + 26248192LL;      // 2097152
    float* aout    = ws + 28345344LL;      // 262144
    float* qatt    = ws + 28607488LL;      // 262144
    float* upd     = ws + 28869632LL;      // 262144
    float* WQE     = ws + 29131776LL;      // 65536
    float* WKE     = ws + 29197312LL;      // 65536
    float* WVE     = ws + 29262848LL;      // 65536
    float* BQE     = ws + 29328384LL;      // 256
    float* BKE     = ws + 29328640LL;      // 256
    float* BVE     = ws + 29328896LL;      // 256
    float* KP = wp;   // wp dead after U gemm
    float* VP = U;    // U dead after sim gemm

    float* outp     = (float*)d_out;
    float* out_ps   = outp;                 // (B,8,256)
    float* out_attn = outp + 262144LL;      // (B,256,1024)
    float* out_slot = outp + 33816576LL;    // (B,8,256)
    float* out_eos  = outp + 34078720LL;    // (B,1,256)

    // 1. word_pe
    word_pe_kernel<<<dim3(BB), dim3(256), 0, stream>>>(txt_emb, txt_mask, word_pe);
    // 2. wp = word_pe @ Wword + b
    gemm_f32<0,0><<<dim3(4,512,1), dim3(256), 0, stream>>>(
        word_pe,256,0, word_proj_w,256,0, word_proj_b, wp,256,0, 32768,256,256);
    // 3. U = wp @ Wvid^T   (sim = U @ video^T + rowshift; rowshift softmax-invariant)
    gemm_f32<1,0><<<dim3(4,512,1), dim3(256), 0, stream>>>(
        wp,256,0, video_proj_w,256,0, nullptr, U,256,0, 32768,256,256);
    // 4. sim = U[b] @ video[b]^T  -> written straight into d_out attn region
    gemm_f32<1,0><<<dim3(16,4,BB), dim3(256), 0, stream>>>(
        U,256,65536LL, video_feats,256,262144LL, nullptr, out_attn,1024,262144LL, 256,1024,256);
    // 5. softmax over T (in place) + entropy
    softmax_entropy_kernel<<<dim3(32768), dim3(256), 0, stream>>>(out_attn, video_mask, ent);
    // 6. greedy selection
    select_kernel<<<dim3(BB), dim3(256), 0, stream>>>(ent, txt_mask, sel);
    // 7. gather phrase slots
    gather_kernel<<<dim3(1024), dim3(256), 0, stream>>>(word_pe, sel, x0);

    float* X = x0;
    for (int i = 0; i < NLAY; ++i) {
        const float* qw  = q_w  + (long long)i * 65536;
        const float* qb  = q_b  + (long long)i * 256;
        const float* kvw = kv_w + (long long)i * 131072;
        const float* kvb = kv_b + (long long)i * 512;
        const float* inw = in_w + (long long)i * 196608;
        const float* inb = in_b + (long long)i * 768;
        const float* ow  = out_w + (long long)i * 65536;
        const float* ob  = out_b + (long long)i * 256;
        const float* g0  = ln0_g + (long long)i * 256;
        const float* b0  = ln0_b + (long long)i * 256;
        const float* lw  = lin_w + (long long)i * 65536;
        const float* lb  = lin_b + (long long)i * 256;
        const float* g1  = ln1_g + (long long)i * 256;
        const float* b1  = ln1_b + (long long)i * 256;

        // effective weights: fold (qw,kvw) into in_w projections (exact linear composition)
        gemm_f32<0,0><<<dim3(4,4,1),dim3(256),0,stream>>>(
            qw,256,0,      inw,768,0,     nullptr, WQE,256,0, 256,256,256);
        gemm_f32<0,0><<<dim3(4,4,1),dim3(256),0,stream>>>(
            kvw,512,0,     inw+256,768,0, nullptr, WKE,256,0, 256,256,256);
        gemm_f32<0,0><<<dim3(4,4,1),dim3(256),0,stream>>>(
            kvw+256,512,0, inw+512,768,0, nullptr, WVE,256,0, 256,256,256);
        eff_bias_kernel<<<dim3(3),dim3(256),0,stream>>>(qb, kvb, inw, inb, BQE, BKE, BVE);

        gemm_f32<0,0><<<dim3(4,16,1),dim3(256),0,stream>>>(
            X,256,0, WQE,256,0, BQE, qp,256,0, 1024,256,256);
        gemm_f32<0,0><<<dim3(4,512,1),dim3(256),0,stream>>>(
            word_pe,256,0, WKE,256,0, BKE, KP,256,0, 32768,256,256);
        gemm_f32<0,0><<<dim3(4,512,1),dim3(256),0,stream>>>(
            word_pe,256,0, WVE,256,0, BVE, VP,256,0, 32768,256,256);

        attn_scores_kernel<<<dim3(BB,NH),dim3(256),0,stream>>>(qp, KP, txt_mask, attnw);
        attn_out_kernel<<<dim3(BB,PP),dim3(256),0,stream>>>(attnw, VP, aout);
        if (i == NLAY - 1)
            slot_sim_kernel<<<dim3(BB,PP),dim3(256),0,stream>>>(attnw, out_slot);

        gemm_f32<0,0><<<dim3(4,16,1),dim3(256),0,stream>>>(
            aout,256,0, ow,256,0, ob, qatt,256,0, 1024,256,256);
        ln_residual_kernel<<<dim3(1024),dim3(256),0,stream>>>(X, qatt, g0, b0, xmid);
        gemm_f32<0,1><<<dim3(4,16,1),dim3(256),0,stream>>>(
            xmid,256,0, lw,256,0, lb, upd,256,0, 1024,256,256);
        float* Xout = (i == NLAY - 1) ? out_ps : ((X == x0) ? x1 : x0);
        ln_residual_kernel<<<dim3(1024),dim3(256),0,stream>>>(xmid, upd, g1, b1, Xout);
        X = Xout;
    }
    eos_kernel<<<dim3(BB),dim3(256),0,stream>>>(eos_slot, out_eos);
}

// Round 3
// 1070.540 us; speedup vs baseline: 1.5980x; 1.5980x over previous
//
#include <hip/hip_runtime.h>
#include <math.h>

// Problem constants (fixed by setup_inputs)
#define BB 128
#define LFULL 257
#define LW 256     // L-1 words
#define TT 1024    // video frames
#define CC 256     // hidden
#define NH 8
#define DHD 32
#define PP 8       // NUM_PHRASE
#define NLAY 3

typedef __bf16 bf16x8 __attribute__((ext_vector_type(8)));
typedef float  f32x4  __attribute__((ext_vector_type(4)));

// ---------------- block reduce helpers (blockDim == 256 -> 4 waves) -------------
__device__ __forceinline__ float blockReduceSum(float v, volatile float* lds) {
#pragma unroll
    for (int m = 32; m >= 1; m >>= 1) v += __shfl_xor(v, m);
    __syncthreads();
    if ((threadIdx.x & 63) == 0) lds[threadIdx.x >> 6] = v;
    __syncthreads();
    return lds[0] + lds[1] + lds[2] + lds[3];
}
__device__ __forceinline__ float blockReduceMax(float v, volatile float* lds) {
#pragma unroll
    for (int m = 32; m >= 1; m >>= 1) v = fmaxf(v, __shfl_xor(v, m));
    __syncthreads();
    if ((threadIdx.x & 63) == 0) lds[threadIdx.x >> 6] = v;
    __syncthreads();
    return fmaxf(fmaxf(lds[0], lds[1]), fmaxf(lds[2], lds[3]));
}

// =================================================================================
// MFMA GEMM: C = A @ B^T (+bias).  A: M x K row-major bf16 (hi[,lo]).
// B: N x K row-major, either bf16 hi[,lo] (B_F32=0) or fp32 split in-kernel (B_F32=1).
// SPLIT=1: split-bf16 product (3 MFMAs: Ahi*Bhi + Ahi*Blo + Alo*Bhi) ~ fp32 accuracy.
// OUT_SPLIT=1: store hi/lo bf16 pair; else fp32.
// 128x128 tile, BK=32, 256 threads (4 waves, 64x64 per wave, 4x4 16x16x32 frags).
// =================================================================================
#define LP 40   // padded LDS row stride (bf16 elems); 80B rows -> 16B aligned

template<int SPLIT, int B_F32, int OUT_SPLIT>
__global__ __launch_bounds__(256) void gemm_mfma(
    const __bf16* __restrict__ Ahi, const __bf16* __restrict__ Alo, int lda, long long sA,
    const void* __restrict__ Bhp, const void* __restrict__ Blp, int ldb, long long sB,
    const float* __restrict__ bias,
    float* __restrict__ Cf, __bf16* __restrict__ Chi, __bf16* __restrict__ Clo,
    int ldc, long long sC, int M, int N, int K)
{
    __shared__ __bf16 sAh[128 * LP];
    __shared__ __bf16 sAl[SPLIT ? 128 * LP : 1];
    __shared__ __bf16 sBh[128 * LP];
    __shared__ __bf16 sBl[SPLIT ? 128 * LP : 1];

    const int tid = threadIdx.x;
    const int n0 = blockIdx.x * 128;
    const int m0 = blockIdx.y * 128;
    const long long bz = blockIdx.z;
    const __bf16* Ah = Ahi + bz * sA;
    const __bf16* Al = SPLIT ? (Alo + bz * sA) : nullptr;

    const int wv = tid >> 6, lane = tid & 63;
    const int wm = (wv & 1) << 6, wn = (wv >> 1) << 6;
    const int lr = lane & 15, quad = lane >> 4;

    // staging indices (bf16 path): 8 elems per load, 2 row-groups
    const int sr = tid >> 2;          // 0..63
    const int sc = (tid & 3) << 3;    // 0,8,16,24
    // staging indices (fp32 B path): 4 elems per load, 4 row-groups
    const int fr = tid >> 3;          // 0..31
    const int fc = (tid & 7) << 2;    // 0..28

    f32x4 acc[4][4];
#pragma unroll
    for (int i = 0; i < 4; ++i)
#pragma unroll
        for (int j = 0; j < 4; ++j) acc[i][j] = (f32x4)(0.f);

    for (int k0 = 0; k0 < K; k0 += 32) {
        // ---- stage A (bf16 hi[,lo]) ----
#pragma unroll
        for (int j = 0; j < 2; ++j) {
            int row = sr + 64 * j;
            *(bf16x8*)&sAh[row * LP + sc] =
                *(const bf16x8*)&Ah[(long long)(m0 + row) * lda + k0 + sc];
            if constexpr (SPLIT)
                *(bf16x8*)&sAl[row * LP + sc] =
                    *(const bf16x8*)&Al[(long long)(m0 + row) * lda + k0 + sc];
        }
        // ---- stage B ----
        if constexpr (B_F32) {
            const float* Bf = (const float*)Bhp + bz * sB;
#pragma unroll
            for (int j = 0; j < 4; ++j) {
                int row = fr + 32 * j;
                float4 f = *(const float4*)&Bf[(long long)(n0 + row) * ldb + k0 + fc];
                __bf16 h0 = (__bf16)f.x, h1 = (__bf16)f.y, h2 = (__bf16)f.z, h3 = (__bf16)f.w;
                sBh[row * LP + fc + 0] = h0; sBh[row * LP + fc + 1] = h1;
                sBh[row * LP + fc + 2] = h2; sBh[row * LP + fc + 3] = h3;
                sBl[row * LP + fc + 0] = (__bf16)(f.x - (float)h0);
                sBl[row * LP + fc + 1] = (__bf16)(f.y - (float)h1);
                sBl[row * LP + fc + 2] = (__bf16)(f.z - (float)h2);
                sBl[row * LP + fc + 3] = (__bf16)(f.w - (float)h3);
            }
        } else {
            const __bf16* Bh = (const __bf16*)Bhp + bz * sB;
#pragma unroll
            for (int j = 0; j < 2; ++j) {
                int row = sr + 64 * j;
                *(bf16x8*)&sBh[row * LP + sc] =
                    *(const bf16x8*)&Bh[(long long)(n0 + row) * ldb + k0 + sc];
                if constexpr (SPLIT) {
                    const __bf16* Bl = (const __bf16*)Blp + bz * sB;
                    *(bf16x8*)&sBl[row * LP + sc] =
                        *(const bf16x8*)&Bl[(long long)(n0 + row) * ldb + k0 + sc];
                }
            }
        }
        __syncthreads();

        // ---- fragments + MFMA ----
        bf16x8 fah[4], fbh[4];
        bf16x8 fal[4], fbl[4];
#pragma unroll
        for (int i = 0; i < 4; ++i) {
            fah[i] = *(const bf16x8*)&sAh[(wm + i * 16 + lr) * LP + quad * 8];
            fbh[i] = *(const bf16x8*)&sBh[(wn + i * 16 + lr) * LP + quad * 8];
            if constexpr (SPLIT) {
                fal[i] = *(const bf16x8*)&sAl[(wm + i * 16 + lr) * LP + quad * 8];
                fbl[i] = *(const bf16x8*)&sBl[(wn + i * 16 + lr) * LP + quad * 8];
            }
        }
#pragma unroll
        for (int i = 0; i < 4; ++i)
#pragma unroll
            for (int j = 0; j < 4; ++j) {
                if constexpr (SPLIT) {
                    acc[i][j] = __builtin_amdgcn_mfma_f32_16x16x32_bf16(fal[i], fbh[j], acc[i][j], 0, 0, 0);
                    acc[i][j] = __builtin_amdgcn_mfma_f32_16x16x32_bf16(fah[i], fbl[j], acc[i][j], 0, 0, 0);
                }
                acc[i][j] = __builtin_amdgcn_mfma_f32_16x16x32_bf16(fah[i], fbh[j], acc[i][j], 0, 0, 0);
            }
        __syncthreads();
    }

    // ---- epilogue: C[row][col], col = lane&15, row = quad*4 + r (m89-verified) ----
#pragma unroll
    for (int i = 0; i < 4; ++i)
#pragma unroll
        for (int j = 0; j < 4; ++j) {
            int col = n0 + wn + j * 16 + lr;
            int row0 = m0 + wm + i * 16 + quad * 4;
            float bv = bias ? bias[col] : 0.f;
#pragma unroll
            for (int r = 0; r < 4; ++r) {
                float v = acc[i][j][r] + bv;
                long long off = (long long)(row0 + r) * ldc + col + bz * sC;
                if constexpr (OUT_SPLIT) {
                    __bf16 h = (__bf16)v;
                    Chi[off] = h;
                    Clo[off] = (__bf16)(v - (float)h);
                } else {
                    Cf[off] = v;
                }
            }
        }
}

// ---------------- fp32 tiled GEMM (small/fold/residual gemms) -------------------
#define GTS 64
#define GKT 16
#define GPAD 68

template<int TRANSB, int RELU, int TRANSC>
__global__ __launch_bounds__(256) void gemm_f32(
    const float* __restrict__ A, int lda, long long sA,
    const float* __restrict__ Bm, int ldb, long long sB,
    const float* __restrict__ bias,
    float* __restrict__ C, int ldc, long long sC,
    int M, int N, int K)
{
    __shared__ float As[GKT][GPAD];
    __shared__ float Bs[GKT][GPAD];
    const int tid = threadIdx.x;
    const int tx = tid & 15, ty = tid >> 4;
    const int n0 = blockIdx.x * GTS;
    const int m0 = blockIdx.y * GTS;
    const long long bz = blockIdx.z;
    const float* Ab = A + bz * sA;
    const float* Bb = Bm + bz * sB;
    float* Cb = C + bz * sC;

    const int lr = tid >> 2;
    const int lc = (tid & 3) << 2;
    const int br = tid >> 4;
    const int bc = (tid & 15) << 2;

    float acc[4][4] = {};

    for (int k0 = 0; k0 < K; k0 += GKT) {
        float4 a = *(const float4*)&Ab[(long long)(m0 + lr) * lda + k0 + lc];
        As[lc + 0][lr] = a.x; As[lc + 1][lr] = a.y;
        As[lc + 2][lr] = a.z; As[lc + 3][lr] = a.w;
        if (TRANSB) {
            float4 b = *(const float4*)&Bb[(long long)(n0 + lr) * ldb + k0 + lc];
            Bs[lc + 0][lr] = b.x; Bs[lc + 1][lr] = b.y;
            Bs[lc + 2][lr] = b.z; Bs[lc + 3][lr] = b.w;
        } else {
            float4 b = *(const float4*)&Bb[(long long)(k0 + br) * ldb + n0 + bc];
            *(float4*)&Bs[br][bc] = b;
        }
        __syncthreads();
#pragma unroll
        for (int k = 0; k < GKT; ++k) {
            float4 av = *(const float4*)&As[k][ty << 2];
            float4 bv = *(const float4*)&Bs[k][tx << 2];
            float ar[4] = {av.x, av.y, av.z, av.w};
            float brr[4] = {bv.x, bv.y, bv.z, bv.w};
#pragma unroll
            for (int i = 0; i < 4; ++i)
#pragma unroll
                for (int j = 0; j < 4; ++j)
                    acc[i][j] = fmaf(ar[i], brr[j], acc[i][j]);
        }
        __syncthreads();
    }

    float bbr[4] = {0.f, 0.f, 0.f, 0.f};
    if (bias) {
        float4 bb = *(const float4*)&bias[n0 + (tx << 2)];
        bbr[0] = bb.x; bbr[1] = bb.y; bbr[2] = bb.z; bbr[3] = bb.w;
    }
#pragma unroll
    for (int i = 0; i < 4; ++i) {
#pragma unroll
        for (int j = 0; j < 4; ++j) {
            float o = acc[i][j] + bbr[j];
            if (RELU) o = fmaxf(o, 0.f);
            if (TRANSC)
                Cb[(long long)(n0 + (tx << 2) + j) * ldc + m0 + (ty << 2) + i] = o;
            else
                Cb[(long long)(m0 + (ty << 2) + i) * ldc + n0 + (tx << 2) + j] = o;
        }
    }
}

// ---------------- word_pe = txt_emb[:,1:] + sine_pos -> split bf16 hi/lo --------
__global__ __launch_bounds__(256) void word_pe_kernel(
    const float* __restrict__ te, const int* __restrict__ tm,
    __bf16* __restrict__ whi, __bf16* __restrict__ wlo)
{
    int b = blockIdx.x;
    int c = threadIdx.x;
    __shared__ float cums[LW];
    const int* m = tm + (long long)b * LFULL + 1;
    int s = 0;
    for (int i = 0; i <= c; ++i) s += (m[i] != 0);
    cums[c] = (float)s;
    __syncthreads();
    int i2 = c & ~1;
    float freq = powf(10000.0f, (float)i2 / (float)CC);
    const float* src = te + ((long long)b * LFULL + 1) * CC + c;
    long long base = (long long)b * LW * CC + c;
    for (int l = 0; l < LW; ++l) {
        float arg = cums[l] / freq;
        float pe = (c & 1) ? cosf(arg) : sinf(arg);
        float v = src[(long long)l * CC] + pe;
        __bf16 h = (__bf16)v;
        whi[base + (long long)l * CC] = h;
        wlo[base + (long long)l * CC] = (__bf16)(v - (float)h);
    }
}

// ---------------- weight prep -------------------------------------------------
__global__ __launch_bounds__(256) void split_transpose_kernel(
    const float* __restrict__ W, __bf16* __restrict__ hi, __bf16* __restrict__ lo)
{
    int n = blockIdx.x, k = threadIdx.x;
    float v = W[(long long)k * CC + n];
    __bf16 h = (__bf16)v;
    hi[(long long)n * CC + k] = h;
    lo[(long long)n * CC + k] = (__bf16)(v - (float)h);
}
__global__ __launch_bounds__(256) void split_plain_kernel(
    const float* __restrict__ W, __bf16* __restrict__ hi, __bf16* __restrict__ lo)
{
    int g = blockIdx.x * 256 + threadIdx.x;
    float v = W[g];
    __bf16 h = (__bf16)v;
    hi[g] = h;
    lo[g] = (__bf16)(v - (float)h);
}
__global__ __launch_bounds__(256) void cvt_bf16_kernel(
    const float* __restrict__ src, __bf16* __restrict__ dst)
{
    int g = blockIdx.x * 256 + threadIdx.x;
    dst[g] = (__bf16)src[g];
}

// ---------------- in-place softmax over T + entropy ----------------------------
__global__ __launch_bounds__(256) void softmax_entropy_kernel(
    float* __restrict__ attn, const int* __restrict__ vmask,
    float* __restrict__ ent)
{
    __shared__ float lds[4];
    long long row = blockIdx.x;
    int b = blockIdx.x >> 8;
    float* p = attn + row * TT;
    const int* m = vmask + (long long)b * TT;
    int t4 = threadIdx.x * 4;
    float4 v = *(const float4*)&p[t4];
    int4 mm4 = *(const int4*)&m[t4];
    float x[4];
    x[0] = mm4.x ? v.x : -INFINITY;
    x[1] = mm4.y ? v.y : -INFINITY;
    x[2] = mm4.z ? v.z : -INFINITY;
    x[3] = mm4.w ? v.w : -INFINITY;
    float mx = fmaxf(fmaxf(x[0], x[1]), fmaxf(x[2], x[3]));
    mx = blockReduceMax(mx, lds);
    float e[4];
    float ps = 0.f;
#pragma unroll
    for (int j = 0; j < 4; ++j) { e[j] = expf(x[j] - mx); ps += e[j]; }
    float sum = blockReduceSum(ps, lds);
    float q[4];
    float ce = 0.f;
#pragma unroll
    for (int j = 0; j < 4; ++j) {
        q[j] = e[j] / sum;
        ce += q[j] * logf(q[j] + 1e-6f);
    }
    ce = blockReduceSum(ce, lds);
    *(float4*)&p[t4] = make_float4(q[0], q[1], q[2], q[3]);
    if (threadIdx.x == 0) ent[row] = -ce;
}

// ---------------- greedy selection ---------------------------------------------
__global__ __launch_bounds__(256) void select_kernel(
    const float* __restrict__ ent, const int* __restrict__ tm,
    int* __restrict__ sel)
{
    int b = blockIdx.x;
    int l = threadIdx.x;
    __shared__ float sc[LW];
    __shared__ int ord[LW];
    __shared__ unsigned char mk[LW];
    mk[l] = (tm[(long long)b * LFULL + 1 + l] != 0);
    sc[l] = mk[l] ? ent[(long long)b * LW + l] : -INFINITY;
    __syncthreads();
    float mys = sc[l];
    int r = 0;
    for (int j = 0; j < LW; ++j) {
        float s = sc[j];
        r += (s > mys) || (s == mys && j < l);
    }
    ord[r] = l;
    __syncthreads();
    if (l == 0) {
        int chosen[PP];
        int cnt = 0;
        for (int t = 0; t < LW; ++t) {
            int idx = ord[t];
            if (!mk[idx]) continue;
            if (cnt >= PP) break;
            bool ok = true;
            for (int s2 = 0; s2 < cnt; ++s2) {
                int d = idx - chosen[s2];
                if (d < 0) d = -d;
                if (d < 2) ok = false;
            }
            if (ok) chosen[cnt++] = idx;
        }
        int last = (cnt > 0) ? chosen[cnt - 1] : -1;
        for (int p = 0; p < PP; ++p)
            sel[b * PP + p] = (p < cnt) ? chosen[p] : last;
    }
}

// ---------------- gather selected rows of word_pe (hi+lo) ----------------------
__global__ __launch_bounds__(256) void gather_kernel(
    const __bf16* __restrict__ whi, const __bf16* __restrict__ wlo,
    const int* __restrict__ sel, float* __restrict__ x0)
{
    int g = blockIdx.x * 256 + threadIdx.x;
    int b = g >> 11;
    int p = (g >> 8) & 7;
    int c = g & 255;
    int idx = sel[b * PP + p];
    if (idx < 0) idx = 0;
    long long off = ((long long)b * LW + idx) * CC + c;
    x0[g] = (float)whi[off] + (float)wlo[off];
}

// ---------------- effective biases ---------------------------------------------
// grid 9: (layer i, role r): r0 -> BQE_all[i*256+..], r1 -> bkv3[i*512+..] (K),
// r2 -> bkv3[i*512+256+..] (V)
__global__ __launch_bounds__(256) void eff_bias_kernel(
    const float* __restrict__ q_b, const float* __restrict__ kv_b,
    const float* __restrict__ in_w, const float* __restrict__ in_b,
    float* __restrict__ BQE_all, float* __restrict__ bkv3)
{
    int i = blockIdx.x / 3;
    int role = blockIdx.x % 3;
    int n = threadIdx.x;
    const float* inw = in_w + (long long)i * 196608;
    const float* inb = in_b + (long long)i * 768;
    const float* srcb;
    int co;
    float* dst;
    if (role == 0)      { srcb = q_b + i * 256;        co = 0;   dst = BQE_all + i * 256; }
    else if (role == 1) { srcb = kv_b + i * 512;       co = 256; dst = bkv3 + i * 512; }
    else                { srcb = kv_b + i * 512 + 256; co = 512; dst = bkv3 + i * 512 + 256; }
    float s = inb[co + n];
    for (int k = 0; k < CC; ++k)
        s = fmaf(srcb[k], inw[(long long)k * 768 + co + n], s);
    dst[n] = s;
}

// ---------------- attention scores + softmax (block per (b,h)); KV ld=512 ------
__global__ __launch_bounds__(256) void attn_scores_kernel(
    const float* __restrict__ qp, const float* __restrict__ KV,
    const int* __restrict__ tm, float* __restrict__ attn)
{
    int b = blockIdx.x, h = blockIdx.y;
    int tid = threadIdx.x;
    __shared__ float qs[PP][DHD];
    __shared__ float sc[PP][LW];
    __shared__ float mxs[PP], sms[PP];
    {
        int q = tid >> 5, d = tid & 31;
        qs[q][d] = qp[((long long)(b * PP + q)) * CC + h * DHD + d];
    }
    __syncthreads();
    const float* kr = KV + ((long long)(b * LW + tid)) * 512 + h * DHD;
    float kreg[DHD];
#pragma unroll
    for (int j = 0; j < 8; ++j) {
        float4 f = *(const float4*)&kr[j * 4];
        kreg[j * 4 + 0] = f.x; kreg[j * 4 + 1] = f.y;
        kreg[j * 4 + 2] = f.z; kreg[j * 4 + 3] = f.w;
    }
    bool mk = tm[(long long)b * LFULL + 1 + tid] != 0;
#pragma unroll
    for (int q = 0; q < PP; ++q) {
        float s = 0.f;
#pragma unroll
        for (int d = 0; d < DHD; ++d) s = fmaf(qs[q][d], kreg[d], s);
        sc[q][tid] = mk ? s * 0.17677669529663687f : -INFINITY;
    }
    __syncthreads();
    {
        int q = tid >> 5, j = tid & 31;
        float m = -INFINITY;
        for (int kk = j; kk < LW; kk += 32) m = fmaxf(m, sc[q][kk]);
#pragma unroll
        for (int mm = 16; mm >= 1; mm >>= 1) m = fmaxf(m, __shfl_xor(m, mm, 32));
        float s = 0.f;
        for (int kk = j; kk < LW; kk += 32) s += expf(sc[q][kk] - m);
#pragma unroll
        for (int mm = 16; mm >= 1; mm >>= 1) s += __shfl_xor(s, mm, 32);
        if (j == 0) { mxs[q] = m; sms[q] = s; }
    }
    __syncthreads();
#pragma unroll
    for (int q = 0; q < PP; ++q) {
        float pv = expf(sc[q][tid] - mxs[q]) / sms[q];
        attn[(((long long)(b * NH + h)) * PP + q) * LW + tid] = pv;
    }
}

// ---------------- attn @ V (block per (b,q)); V at KV col offset 256 -----------
__global__ __launch_bounds__(256) void attn_out_kernel(
    const float* __restrict__ attn, const float* __restrict__ KV,
    float* __restrict__ aout)
{
    int b = blockIdx.x, q = blockIdx.y;
    int c = threadIdx.x, h = c >> 5;
    __shared__ float att[NH][LW];
#pragma unroll
    for (int hh = 0; hh < NH; ++hh)
        att[hh][c] = attn[(((long long)(b * NH + hh)) * PP + q) * LW + c];
    __syncthreads();
    const float* vpb = KV + ((long long)b * LW) * 512 + 256 + c;
    float acc = 0.f;
#pragma unroll 8
    for (int k = 0; k < LW; ++k)
        acc = fmaf(att[h][k], vpb[(long long)k * 512], acc);
    aout[((long long)(b * PP + q)) * CC + c] = acc;
}

// ---------------- slot_sim = mean over heads -----------------------------------
__global__ __launch_bounds__(256) void slot_sim_kernel(
    const float* __restrict__ attn, float* __restrict__ outs)
{
    int b = blockIdx.x, q = blockIdx.y, k = threadIdx.x;
    float s = 0.f;
#pragma unroll
    for (int h = 0; h < NH; ++h)
        s += attn[(((long long)(b * NH + h)) * PP + q) * LW + k];
    outs[((long long)(b * PP + q)) * LW + k] = s * 0.125f;
}

// ---------------- residual + layer norm ----------------------------------------
__global__ __launch_bounds__(256) void ln_residual_kernel(
    const float* __restrict__ xin, const float* __restrict__ add,
    const float* __restrict__ g, const float* __restrict__ bta,
    float* __restrict__ out)
{
    __shared__ float lds[4];
    int r = blockIdx.x, c = threadIdx.x;
    long long idx = (long long)r * CC + c;
    float v = xin[idx] + add[idx];
    float s = blockReduceSum(v, lds);
    float mu = s * (1.0f / (float)CC);
    float d = v - mu;
    float var = blockReduceSum(d * d, lds) * (1.0f / (float)CC);
    out[idx] = d / sqrtf(var + 1e-5f) * g[c] + bta[c];
}

// ---------------- eos broadcast -------------------------------------------------
__global__ __launch_bounds__(256) void eos_kernel(
    const float* __restrict__ eos, float* __restrict__ outp)
{
    outp[(long long)blockIdx.x * CC + threadIdx.x] = eos[threadIdx.x];
}

// =================================================================================
extern "C" void kernel_launch(void* const* d_in, const int* in_sizes, int n_in,
                              void* d_out, int out_size, void* d_ws, size_t ws_size,
                              hipStream_t stream) {
    const float* txt_emb     = (const float*)d_in[0];
    const int*   txt_mask    = (const int*)d_in[1];
    const float* video_feats = (const float*)d_in[2];
    const int*   video_mask  = (const int*)d_in[3];
    const float* word_proj_w = (const float*)d_in[4];
    const float* word_proj_b = (const float*)d_in[5];
    const float* video_proj_w = (const float*)d_in[6];
    // video_proj_b drops out (softmax shift invariance)
    const float* q_w   = (const float*)d_in[8];
    const float* q_b   = (const float*)d_in[9];
    const float* kv_w  = (const float*)d_in[10];
    const float* kv_b  = (const float*)d_in[11];
    const float* in_w  = (const float*)d_in[12];
    const float* in_b  = (const float*)d_in[13];
    const float* out_w = (const float*)d_in[14];
    const float* out_b = (const float*)d_in[15];
    const float* ln0_g = (const float*)d_in[16];
    const float* ln0_b = (const float*)d_in[17];
    const float* lin_w = (const float*)d_in[18];
    const float* lin_b = (const float*)d_in[19];
    const float* ln1_g = (const float*)d_in[20];
    const float* ln1_b = (const float*)d_in[21];
    const float* eos_slot = (const float*)d_in[22];

    // workspace layout (float units, ~120 MiB)
    float* ws = (float*)d_ws;
    __bf16* wpe_hi = (__bf16*)(ws + 0LL);          // 8388608 bf16
    __bf16* wpe_lo = (__bf16*)(ws + 4194304LL);    // 8388608 bf16
    // R1 region: wp/U split pairs, later reused as KV fp32 (wp/U dead after sim)
    __bf16* wp_hi  = (__bf16*)(ws + 8388608LL);
    __bf16* wp_lo  = (__bf16*)(ws + 12582912LL);
    __bf16* U_hi   = (__bf16*)(ws + 16777216LL);
    __bf16* U_lo   = (__bf16*)(ws + 20971520LL);
    float*  KV     = ws + 8388608LL;               // 32768x512 fp32 (overlaps wp/U)
    float* ent     = ws + 25165824LL;              // 32768
    int*   sel     = (int*)(ws + 25198592LL);      // 1024
    float* x0      = ws + 25199616LL;
    float* x1      = ws + 25461760LL;
    float* xmid    = ws + 25723904LL;
    float* qp      = ws + 25986048LL;
    float* attnw   = ws + 26248192LL;              // 2097152
    float* aout    = ws + 28345344LL;
    float* qatt    = ws + 28607488LL;
    float* upd     = ws + 28869632LL;
    float* WQE_all = ws + 29131776LL;              // 3*65536
    float* BQE_all = ws + 29328384LL;              // 768
    float* WT3f    = ws + 29329152LL;              // 393216 (3 layers x [512][256])
    __bf16* WT3    = (__bf16*)(ws + 29722368LL);   // 393216 bf16
    float* bkv3    = ws + 29918976LL;              // 1536
    __bf16* WPT_hi = (__bf16*)(ws + 29920512LL);   // 65536 bf16
    __bf16* WPT_lo = (__bf16*)(ws + 29953280LL);
    __bf16* VPS_hi = (__bf16*)(ws + 29986048LL);
    __bf16* VPS_lo = (__bf16*)(ws + 30018816LL);

    float* outp     = (float*)d_out;
    float* out_ps   = outp;
    float* out_attn = outp + 262144LL;
    float* out_slot = outp + 33816576LL;
    float* out_eos  = outp + 34078720LL;

    // 1. word_pe (split bf16)
    word_pe_kernel<<<dim3(BB), dim3(256), 0, stream>>>(txt_emb, txt_mask, wpe_hi, wpe_lo);
    // 2. weight preps
    split_transpose_kernel<<<dim3(256), dim3(256), 0, stream>>>(word_proj_w, WPT_hi, WPT_lo);
    split_plain_kernel<<<dim3(256), dim3(256), 0, stream>>>(video_proj_w, VPS_hi, VPS_lo);
    // 3. wp = word_pe @ Wword + b   (split x split -> split out)
    gemm_mfma<1,0,1><<<dim3(2,256,1), dim3(256), 0, stream>>>(
        wpe_hi, wpe_lo, 256, 0, WPT_hi, WPT_lo, 256, 0, word_proj_b,
        nullptr, wp_hi, wp_lo, 256, 0, 32768, 256, 256);
    // 4. U = wp @ Wvid^T            (split x split -> split out)
    gemm_mfma<1,0,1><<<dim3(2,256,1), dim3(256), 0, stream>>>(
        wp_hi, wp_lo, 256, 0, VPS_hi, VPS_lo, 256, 0, nullptr,
        nullptr, U_hi, U_lo, 256, 0, 32768, 256, 256);
    // 5. sim = U[b] @ video[b]^T    (split x fp32-in-kernel -> fp32 out_attn)
    gemm_mfma<1,1,0><<<dim3(8,2,BB), dim3(256), 0, stream>>>(
        U_hi, U_lo, 256, 65536LL, video_feats, nullptr, 256, 262144LL, nullptr,
        out_attn, nullptr, nullptr, 1024, 262144LL, 256, 1024, 256);
    // 6. softmax + entropy (in place)
    softmax_entropy_kernel<<<dim3(32768), dim3(256), 0, stream>>>(out_attn, video_mask, ent);
    // 7. selection + gather
    select_kernel<<<dim3(BB), dim3(256), 0, stream>>>(ent, txt_mask, sel);
    gather_kernel<<<dim3(1024), dim3(256), 0, stream>>>(wpe_hi, wpe_lo, sel, x0);

    // 8. folded weights (all layers, z-batched)
    gemm_f32<0,0,0><<<dim3(4,4,3), dim3(256), 0, stream>>>(
        q_w,256,65536LL, in_w,768,196608LL, nullptr, WQE_all,256,65536LL, 256,256,256);
    gemm_f32<0,0,1><<<dim3(4,4,3), dim3(256), 0, stream>>>(          // K fold, transposed out
        kv_w,512,131072LL, in_w+256,768,196608LL, nullptr, WT3f,256,131072LL, 256,256,256);
    gemm_f32<0,0,1><<<dim3(4,4,3), dim3(256), 0, stream>>>(          // V fold, transposed out
        kv_w+256,512,131072LL, in_w+512,768,196608LL, nullptr, WT3f+65536,256,131072LL, 256,256,256);
    eff_bias_kernel<<<dim3(9), dim3(256), 0, stream>>>(q_b, kv_b, in_w, in_b, BQE_all, bkv3);
    cvt_bf16_kernel<<<dim3(1536), dim3(256), 0, stream>>>(WT3f, (__bf16*)WT3);

    float* X = x0;
    for (int i = 0; i < NLAY; ++i) {
        const float* ow  = out_w + (long long)i * 65536;
        const float* ob  = out_b + (long long)i * 256;
        const float* g0  = ln0_g + (long long)i * 256;
        const float* b0  = ln0_b + (long long)i * 256;
        const float* lw  = lin_w + (long long)i * 65536;
        const float* lb  = lin_b + (long long)i * 256;
        const float* g1  = ln1_g + (long long)i * 256;
        const float* b1  = ln1_b + (long long)i * 256;

        // KV = word_pe @ [WK|WV]^T + bias   (plain bf16 MFMA; overwrites wp/U region)
        gemm_mfma<0,0,0><<<dim3(4,256,1), dim3(256), 0, stream>>>(
            wpe_hi, nullptr, 256, 0, WT3 + (long long)i * 131072, nullptr, 256, 0,
            bkv3 + i * 512, KV, nullptr, nullptr, 512, 0, 32768, 512, 256);

        gemm_f32<0,0,0><<<dim3(4,16,1), dim3(256), 0, stream>>>(
            X,256,0, WQE_all + (long long)i*65536,256,0, BQE_all + i*256, qp,256,0, 1024,256,256);

        attn_scores_kernel<<<dim3(BB,NH), dim3(256), 0, stream>>>(qp, KV, txt_mask, attnw);
        attn_out_kernel<<<dim3(BB,PP), dim3(256), 0, stream>>>(attnw, KV, aout);
        if (i == NLAY - 1)
            slot_sim_kernel<<<dim3(BB,PP), dim3(256), 0, stream>>>(attnw, out_slot);

        gemm_f32<0,0,0><<<dim3(4,16,1), dim3(256), 0, stream>>>(
            aout,256,0, ow,256,0, ob, qatt,256,0, 1024,256,256);
        ln_residual_kernel<<<dim3(1024), dim3(256), 0, stream>>>(X, qatt, g0, b0, xmid);
        gemm_f32<0,1,0><<<dim3(4,16,1), dim3(256), 0, stream>>>(
            xmid,256,0, lw,256,0, lb, upd,256,0, 1024,256,256);
        float* Xout = (i == NLAY - 1) ? out_ps : ((X == x0) ? x1 : x0);
        ln_residual_kernel<<<dim3(1024), dim3(256), 0, stream>>>(xmid, upd, g1, b1, Xout);
        X = Xout;
    }
    eos_kernel<<<dim3(BB), dim3(256), 0, stream>>>(eos_slot, out_eos);
}